// Round 14
// baseline (185.114 us; speedup 1.0000x reference)
//
#include <hip/hip_runtime.h>
#include <cstdint>
#include <cstddef>

typedef unsigned short u16;
typedef __bf16 bf16x8 __attribute__((ext_vector_type(8)));
typedef __bf16 bf16x2 __attribute__((ext_vector_type(2)));
typedef float f32x4 __attribute__((ext_vector_type(4)));
typedef float f32x16 __attribute__((ext_vector_type(16)));

#define B_   4
#define T_   2048
#define H_   1024
#define NH_  16
#define DH_  64
#define M_   (B_ * T_)      // 8192
#define KDIM 1024
// SCALE * log2(e): scores computed directly in log2 domain
#define QSCALE 0.18033688011112042f

#define BM 128
#define BN 128
#define BK 32

__device__ __forceinline__ u16 f2bf(float f) {
    unsigned u = __float_as_uint(f);
    unsigned r = (u + 0x7fffu + ((u >> 16) & 1u)) >> 16;  // RNE
    return (u16)r;
}

__device__ __forceinline__ unsigned packbf2(float a, float b) {
    bf16x2 v = { (__bf16)a, (__bf16)b };   // compiler emits v_cvt_pk_bf16_f32
    return __builtin_bit_cast(unsigned, v);
}

__device__ __forceinline__ float exp2_fast(float x) {
#if __has_builtin(__builtin_amdgcn_exp2f)
    return __builtin_amdgcn_exp2f(x);
#else
    return exp2f(x);
#endif
}

// in-place half-wave swap
__device__ __forceinline__ void plswap(unsigned &a, unsigned &b) {
#if __has_builtin(__builtin_amdgcn_permlane32_swap)
    auto r = __builtin_amdgcn_permlane32_swap(a, b, false, false);
    a = (unsigned)r[0]; b = (unsigned)r[1];
#else
    int hi = (threadIdx.x & 32);
    unsigned x = (unsigned)__shfl_xor((int)(hi ? b : a), 32);
    unsigned na = hi ? x : a;
    unsigned nb = hi ? b : x;
    a = na; b = nb;
#endif
}

__device__ __forceinline__ void gload16(const void* g, void* l) {
    __builtin_amdgcn_global_load_lds(
        (const __attribute__((address_space(1))) unsigned int*)g,
        (__attribute__((address_space(3))) unsigned int*)l,
        16, 0, 0);
}

__device__ __forceinline__ f32x16 mfma32(bf16x8 a, bf16x8 b, f32x16 c) {
    return __builtin_amdgcn_mfma_f32_32x32x16_bf16(a, b, c, 0, 0, 0);
}

// ---------------- fp32 -> bf16 converts (single launch, 6 jobs) ----------------
__global__ __launch_bounds__(256) void f2bf_hex(
    const float* s0, u16* d0, int n0, const float* s1, u16* d1, int n1,
    const float* s2, u16* d2, int n2, const float* s3, u16* d3, int n3,
    const float* s4, u16* d4, int n4j, const float* s5, u16* d5, int n5)
{
    const float* s; u16* d; int n;
    switch (blockIdx.y) {
        case 0: s = s0; d = d0; n = n0; break;
        case 1: s = s1; d = d1; n = n1; break;
        case 2: s = s2; d = d2; n = n2; break;
        case 3: s = s3; d = d3; n = n3; break;
        case 4: s = s4; d = d4; n = n4j; break;
        default: s = s5; d = d5; n = n5; break;
    }
    int i = blockIdx.x * blockDim.x + threadIdx.x;
    int stride = gridDim.x * blockDim.x;
    for (; i < n; i += stride) {
        float4 f = reinterpret_cast<const float4*>(s)[i];
        ushort4 o;
        o.x = f2bf(f.x); o.y = f2bf(f.y); o.z = f2bf(f.z); o.w = f2bf(f.w);
        reinterpret_cast<ushort4*>(d)[i] = o;
    }
}

// ---------------- 128x128 bf16 GEMM core v3  C = X * W^T ----------------
// 2 waves/block (128 thr), wave-tile 64x128: a[4]+b[8] = 12 ds_read_b128
// feed 32 MFMAs (42.7 FLOP/LDS-byte, +33% vs 4-wave 64x64) — GEMM is
// LDS-read-BW-bound (per CU: 1152 LDS-cyc vs 384 MFMA-cyc per K-step).
// T4 counted-vmcnt triple-buffer kept verbatim; 8 loads/thread/stage ->
// vmcnt(8). Grid 1536 = clean 2 rounds at 3 blocks/CU (LDS 48KB).
__device__ __forceinline__ void gemm_core(
    const u16* __restrict__ X, const u16* __restrict__ W,
    const float* __restrict__ bias,
    u16* __restrict__ dst_bf, float* __restrict__ dst_f,
    float scale, int mode, int r0, int c0)
{
    __shared__ u16 lds[24576];   // 49,152 B: 3 staging buffers x 16KB
    char* const base = (char*)lds;

    const int tid = threadIdx.x;   // 0..127
    const int wid = tid >> 6;      // 0..1
    const int l15 = tid & 15;
    const int l4  = (tid & 63) >> 4;

    const u16* gA = X + (size_t)(r0 + (tid >> 2)) * KDIM + (tid & 3) * 8;
    const u16* gB = W + (size_t)(c0 + (tid >> 2)) * KDIM + (tid & 3) * 8;

    f32x4 acc[4][8];
#pragma unroll
    for (int m = 0; m < 4; ++m)
#pragma unroll
        for (int n = 0; n < 8; ++n) acc[m][n] = (f32x4){0.f, 0.f, 0.f, 0.f};

    const int arow = wid * 64 + l15;

    // staging: buffer p: A @ p*16384 ([128 rows][64B]), B @ +8192.
    // 128 threads x 8 gload16; thread tid writes rows (tid>>2)+{0,32,64,96}.
#define STAGEG(p, kt) do { \
    const u16* pa_ = gA + (kt) * BK; \
    const u16* pb_ = gB + (kt) * BK; \
    char* dA_ = base + (p) * 16384 + wid * 1024; \
    char* dB_ = dA_ + 8192; \
    gload16(pa_, dA_);                    gload16(pa_ + 32 * KDIM, dA_ + 2048); \
    gload16(pa_ + 64 * KDIM, dA_ + 4096); gload16(pa_ + 96 * KDIM, dA_ + 6144); \
    gload16(pb_, dB_);                    gload16(pb_ + 32 * KDIM, dB_ + 2048); \
    gload16(pb_ + 64 * KDIM, dB_ + 4096); gload16(pb_ + 96 * KDIM, dB_ + 6144); \
} while (0)

#define COMPUTE(p) do { \
    const char* bufp = base + (p) * 16384; \
    bf16x8 a[4], b[8]; \
    _Pragma("unroll") \
    for (int m = 0; m < 4; ++m) \
        a[m] = *(const bf16x8*)(bufp + (arow + m * 16) * 64 + l4 * 16); \
    _Pragma("unroll") \
    for (int n = 0; n < 8; ++n) \
        b[n] = *(const bf16x8*)(bufp + 8192 + (n * 16 + l15) * 64 + l4 * 16); \
    _Pragma("unroll") \
    for (int m = 0; m < 4; ++m) \
        _Pragma("unroll") \
        for (int n = 0; n < 8; ++n) \
            acc[m][n] = __builtin_amdgcn_mfma_f32_16x16x32_bf16(a[m], b[n], acc[m][n], 0, 0, 0); \
    } while (0)

    STAGEG(0, 0);
    STAGEG(1, 1);

    int p = 0;
    for (int kt = 0; kt < KDIM / BK - 1; ++kt) {
        asm volatile("s_waitcnt vmcnt(8) lgkmcnt(0)\n\ts_barrier" ::: "memory");
        if (kt + 2 < KDIM / BK) {
            int fp = p + 2; if (fp >= 3) fp -= 3;
            STAGEG(fp, kt + 2);
        }
        COMPUTE(p);
        ++p; if (p == 3) p = 0;
    }
    asm volatile("s_waitcnt vmcnt(0) lgkmcnt(0)\n\ts_barrier" ::: "memory");
    COMPUTE(p);
#undef COMPUTE
#undef STAGEG

    if (mode == 2) {
#pragma unroll
        for (int m = 0; m < 4; ++m)
#pragma unroll
            for (int n = 0; n < 8; ++n) {
                int cg = c0 + n * 16 + l15;
                float bv = bias[cg];
                int rg = r0 + wid * 64 + m * 16 + l4 * 4;
#pragma unroll
                for (int j = 0; j < 4; ++j)
                    dst_f[(size_t)(rg + j) * H_ + cg] = acc[m][n][j] + bv;
            }
    } else if (mode == 0) {
        // stage C row-major in LDS ([128][136] u16), 16B coalesced stores
        __syncthreads();
        u16 (*ldsR)[136] = (u16(*)[136])lds;
#pragma unroll
        for (int m = 0; m < 4; ++m)
#pragma unroll
            for (int n = 0; n < 8; ++n) {
                int cl = n * 16 + l15;
                float bv = bias[c0 + cl];
                int rl = wid * 64 + m * 16 + l4 * 4;
#pragma unroll
                for (int j = 0; j < 4; ++j)
                    ldsR[rl + j][cl] = f2bf((acc[m][n][j] + bv) * scale);
            }
        __syncthreads();
        int b2 = r0 >> 11, tb = r0 & (T_ - 1);
#pragma unroll
        for (int it = 0; it < 16; ++it) {
            int id = tid + it * 128;          // 0..2047
            int row = id >> 4;                // 0..127
            int ch = id & 15;                 // 0..15
            int head = (c0 >> 6) + (ch >> 3);
            int d0 = (ch & 7) * 8;
            uint4 v = *(const uint4*)&ldsR[row][ch * 8];
            *(uint4*)&dst_bf[(((size_t)(b2 * NH_ + head) * T_ + tb + row) << 6) + d0] = v;
        }
    } else {
        __syncthreads();
        u16 (*ldsT)[136] = (u16(*)[136])lds;
#pragma unroll
        for (int m = 0; m < 4; ++m)
#pragma unroll
            for (int n = 0; n < 8; ++n) {
                int cl = n * 16 + l15;
                float bv = bias[c0 + cl];
                int rl = wid * 64 + m * 16 + l4 * 4;
#pragma unroll
                for (int j = 0; j < 4; ++j)
                    ldsT[cl][rl + j] = f2bf(acc[m][n][j] + bv);
            }
        __syncthreads();
        int b = r0 >> 11, tb = r0 & (T_ - 1);
#pragma unroll
        for (int it = 0; it < 16; ++it) {
            int chunk = tid + it * 128;
            int cl = chunk >> 4;
            int r8 = (chunk & 15) << 3;
            int cg = c0 + cl;
            int head = cg >> 6, d = cg & 63;
            uint4 v = *(const uint4*)&ldsT[cl][r8];
            *(uint4*)&dst_bf[((size_t)((b * NH_ + head) * DH_ + d) * T_) + tb + r8] = v;
        }
    }
}

// Fused QKV projection: grid (24,64), 128 threads. bx 0-7: Q, 8-15: K, 16-23: V.
__global__ __launch_bounds__(128, 2) void gemm_qkv(
    const u16* __restrict__ qbf, const u16* __restrict__ vbf,
    const u16* __restrict__ Wqb, const u16* __restrict__ Wkb, const u16* __restrict__ Wvb,
    const float* __restrict__ bq, const float* __restrict__ bk, const float* __restrict__ bv,
    u16* __restrict__ Qd, u16* __restrict__ Kd, u16* __restrict__ Vtd)
{
    const int orig = blockIdx.y * 24 + blockIdx.x;
    const int swz = (orig & 7) * 192 + (orig >> 3);
    const int bx = swz % 24;
    const int by = swz / 24;
    const int seg = bx >> 3;
    const int r0 = by * BM;
    const int c0 = (bx & 7) * BN;

    if (seg == 0)
        gemm_core(qbf, Wqb, bq, Qd, nullptr, QSCALE, 0, r0, c0);
    else if (seg == 1)
        gemm_core(vbf, Wkb, bk, Kd, nullptr, 1.0f, 0, r0, c0);
    else
        gemm_core(vbf, Wvb, bv, Vtd, nullptr, 1.0f, 1, r0, c0);
}

// Output projection: grid (8,64), 128 threads. XCD swizzle chunk=64.
__global__ __launch_bounds__(128, 2) void gemm_out(
    const u16* __restrict__ AO, const u16* __restrict__ Wob,
    const float* __restrict__ bo, float* __restrict__ out)
{
    const int orig = blockIdx.y * 8 + blockIdx.x;
    const int swz = (orig & 7) * 64 + (orig >> 3);
    const int bx = swz & 7;
    const int by = swz >> 3;
    gemm_core(AO, Wob, bo, nullptr, out, 1.0f, 2, by * BM, bx * BN);
}

// ---------------- flash attention: swapped-operand 32x32, Q-width 64 ----
// R6/R10-proven 82.7us kernel (dual-buffer, 32KB LDS, VGPR 116). Structural
// floor: 116 arch + 64 acc = 180 unified regs -> 2 waves/SIMD bucket; 74%
// combined MFMA+VALU issue = this structure's ceiling (verified R4/R6/R9/R11).
#define KVB 64

__global__ __launch_bounds__(256, 2) void attn64(
    const u16* __restrict__ Q, const u16* __restrict__ K,
    const u16* __restrict__ Vt, u16* __restrict__ AO)
{
    __shared__ u16 lds[16384];
    char* const base = (char*)lds;

    const int tid = threadIdx.x;
    const int wid = tid >> 6;
    const int lane = tid & 63;
    const int l31 = lane & 31;
    const int hi = lane >> 5;

    const int orig = blockIdx.y * 8 + blockIdx.x;
    const int swz = (orig & 7) * 64 + (orig >> 3);
    const int bn = swz >> 3;
    const int q0w = (swz & 7) * 256 + wid * 64;
    const int b = bn >> 4, head = bn & 15;

    const u16* Qb = Q + ((size_t)bn * T_ + q0w + l31) * DH_;
    const u16* Kb = K + (size_t)bn * T_ * DH_;
    const u16* Vb = Vt + (size_t)bn * DH_ * T_;

    bf16x8 qfa[4], qfb[4];
#pragma unroll
    for (int c = 0; c < 4; ++c) {
        qfa[c] = *(const bf16x8*)(Qb + c * 16 + hi * 8);
        qfb[c] = *(const bf16x8*)(Qb + 32 * DH_ + c * 16 + hi * 8);
    }

    f32x16 accO00, accO01, accO10, accO11;
#pragma unroll
    for (int r = 0; r < 16; ++r) {
        accO00[r] = 0.f; accO01[r] = 0.f;
        accO10[r] = 0.f; accO11[r] = 0.f;
    }
    float la = 0.f, lb = 0.f;

    const int srow = tid >> 3;
    const int scsw = (tid & 7) ^ (srow & 7);
    const int rowsw = l31 & 7;

    const u16* kSrc = Kb + (size_t)srow * DH_ + scsw * 8;
    const u16* vSrc = Vb + (size_t)srow * T_ + scsw * 8;

#define STAGE(dK, dV) do { \
    gload16(kSrc,            (dK) + tid * 16); \
    gload16(kSrc + 32 * DH_, (dK) + 4096 + tid * 16); \
    gload16(vSrc,            (dV) + tid * 16); \
    gload16(vSrc + 32 * T_,  (dV) + 4096 + tid * 16); \
    kSrc += KVB * DH_; vSrc += KVB; } while (0)

    char* const kb0 = base;
    char* const vb0 = base + 8192;
    char* const kb1 = base + 16384;
    char* const vb1 = base + 24576;

    auto process = [&](const char* kc, const char* vc) {
        f32x16 sA0, sA1, sB0, sB1;
#pragma unroll
        for (int r = 0; r < 16; ++r) { sA0[r] = 0.f; sA1[r] = 0.f; sB0[r] = 0.f; sB1[r] = 0.f; }
        __builtin_amdgcn_s_setprio(1);
#pragma unroll
        for (int c = 0; c < 4; ++c) {
            const int c16 = ((2 * c + hi) ^ rowsw) * 16;
            bf16x8 k0 = *(const bf16x8*)(kc + l31 * 128 + c16);
            bf16x8 k1 = *(const bf16x8*)(kc + 4096 + l31 * 128 + c16);
            sA0 = mfma32(k0, qfa[c], sA0);
            sA1 = mfma32(k1, qfa[c], sA1);
            sB0 = mfma32(k0, qfb[c], sB0);
            sB1 = mfma32(k1, qfb[c], sB1);
        }
        __builtin_amdgcn_s_setprio(0);

#pragma unroll
        for (int r = 0; r < 16; ++r) {
            sA0[r] = exp2_fast(sA0[r]);
            sA1[r] = exp2_fast(sA1[r]);
            sB0[r] = exp2_fast(sB0[r]);
            sB1[r] = exp2_fast(sB1[r]);
        }
        float ta = 0.f, tb2 = 0.f;
#pragma unroll
        for (int r = 0; r < 16; ++r) {
            ta  += sA0[r] + sA1[r];
            tb2 += sB0[r] + sB1[r];
        }
        la += ta; lb += tb2;

        unsigned w0a[8], w1a[8], w0b[8], w1b[8];
#pragma unroll
        for (int k2 = 0; k2 < 8; ++k2) {
            w0a[k2] = packbf2(sA0[2 * k2], sA0[2 * k2 + 1]);
            w1a[k2] = packbf2(sA1[2 * k2], sA1[2 * k2 + 1]);
            w0b[k2] = packbf2(sB0[2 * k2], sB0[2 * k2 + 1]);
            w1b[k2] = packbf2(sB1[2 * k2], sB1[2 * k2 + 1]);
        }
        plswap(w0a[0], w0a[2]); plswap(w0a[1], w0a[3]);
        plswap(w0a[4], w0a[6]); plswap(w0a[5], w0a[7]);
        plswap(w1a[0], w1a[2]); plswap(w1a[1], w1a[3]);
        plswap(w1a[4], w1a[6]); plswap(w1a[5], w1a[7]);
        plswap(w0b[0], w0b[2]); plswap(w0b[1], w0b[3]);
        plswap(w0b[4], w0b[6]); plswap(w0b[5], w0b[7]);
        plswap(w1b[0], w1b[2]); plswap(w1b[1], w1b[3]);
        plswap(w1b[4], w1b[6]); plswap(w1b[5], w1b[7]);

        __builtin_amdgcn_s_setprio(1);
#pragma unroll
        for (int ks = 0; ks < 4; ++ks) {
            union { unsigned w[4]; bf16x8 v; } pa, pb;
            const unsigned* sa_ = (ks < 2) ? w0a : w1a;
            const unsigned* sb_ = (ks < 2) ? w0b : w1b;
            const int o = (ks & 1) * 4;
            pa.w[0] = sa_[o + 0]; pa.w[1] = sa_[o + 1];
            pa.w[2] = sa_[o + 2]; pa.w[3] = sa_[o + 3];
            pb.w[0] = sb_[o + 0]; pb.w[1] = sb_[o + 1];
            pb.w[2] = sb_[o + 2]; pb.w[3] = sb_[o + 3];
            const int c16 = ((2 * ks + hi) ^ rowsw) * 16;
            bf16x8 v0f = *(const bf16x8*)(vc + l31 * 128 + c16);
            bf16x8 v1f = *(const bf16x8*)(vc + 4096 + l31 * 128 + c16);
            accO00 = mfma32(v0f, pa.v, accO00);
            accO01 = mfma32(v1f, pa.v, accO01);
            accO10 = mfma32(v0f, pb.v, accO10);
            accO11 = mfma32(v1f, pb.v, accO11);
        }
        __builtin_amdgcn_s_setprio(0);
    };

    STAGE(kb0, vb0);
    __syncthreads();

    for (int it = 0; it < T_ / KVB; it += 2) {
        STAGE(kb1, vb1);
        process(kb0, vb0);
        __syncthreads();
        if (it + 2 < T_ / KVB) STAGE(kb0, vb0);
        process(kb1, vb1);
        __syncthreads();
    }

    la += __shfl_xor(la, 32);
    lb += __shfl_xor(lb, 32);

    char* myO = base + wid * 8192;
    float inva = 1.f / la;
    float invb = 1.f / lb;
#pragma unroll
    for (int n = 0; n < 2; ++n)
#pragma unroll
        for (int r = 0; r < 16; ++r) {
            int d = n * 32 + (r & 3) + 8 * (r >> 2) + 4 * hi;
            int c16 = (d >> 3) ^ rowsw;
            float va = (n == 0 ? accO00[r] : accO01[r]) * inva;
            float vb2 = (n == 0 ? accO10[r] : accO11[r]) * invb;
            *(u16*)(myO + l31 * 128 + c16 * 16 + (d & 7) * 2) = f2bf(va);
            *(u16*)(myO + (32 + l31) * 128 + c16 * 16 + (d & 7) * 2) = f2bf(vb2);
        }
    asm volatile("s_waitcnt lgkmcnt(0)" ::: "memory");
#pragma unroll
    for (int it = 0; it < 8; ++it) {
        int id = lane + it * 64;
        int row = id >> 3;
        int c = id & 7;
        int c16s = c ^ (row & 7);
        uint4 val = *(const uint4*)(myO + row * 128 + c16s * 16);
        *(uint4*)&AO[(size_t)(b * T_ + q0w + row) * (NH_ * DH_) + head * DH_ + c * 8] = val;
    }
#undef STAGE
}

// ---------------- host launch ----------------
extern "C" void kernel_launch(void* const* d_in, const int* in_sizes, int n_in,
                              void* d_out, int out_size, void* d_ws, size_t ws_size,
                              hipStream_t stream)
{
    const float* query = (const float*)d_in[0];
    const float* value = (const float*)d_in[1];
    const float* Wq = (const float*)d_in[2];
    const float* bq = (const float*)d_in[3];
    const float* Wk = (const float*)d_in[4];
    const float* bk = (const float*)d_in[5];
    const float* Wv = (const float*)d_in[6];
    const float* bv = (const float*)d_in[7];
    const float* Wo = (const float*)d_in[8];
    const float* bo = (const float*)d_in[9];
    float* out = (float*)d_out;

    u16* ws = (u16*)d_ws;
    const size_t E8M = (size_t)8 << 20;
    u16* qbf = ws;
    u16* vbf = ws + E8M;
    u16* Wqb = ws + 2 * E8M;
    u16* Wkb = Wqb + (1u << 20);
    u16* Wvb = Wkb + (1u << 20);
    u16* Wob = Wvb + (1u << 20);
    u16* Qd  = Wob + (1u << 20);
    u16* Kd  = Qd + E8M;
    u16* Vtd = Kd + E8M;
    u16* AO  = Vtd + E8M;

    const int nBig = (B_ * T_ * H_) / 4;
    const int nW   = (KDIM * KDIM) / 4;
    f2bf_hex<<<dim3(512, 6), 256, 0, stream>>>(
        query, qbf, nBig, value, vbf, nBig,
        Wq, Wqb, nW, Wk, Wkb, nW, Wv, Wvb, nW, Wo, Wob, nW);

    gemm_qkv<<<dim3(24, 64), 128, 0, stream>>>(qbf, vbf, Wqb, Wkb, Wvb,
                                               bq, bk, bv, Qd, Kd, Vtd);

    attn64<<<dim3(8, 64), 256, 0, stream>>>(Qd, Kd, Vtd, AO);

    gemm_out<<<dim3(8, 64), 128, 0, stream>>>(AO, Wob, bo, out);
}

// Round 15
// 183.350 us; speedup vs baseline: 1.0096x; 1.0096x over previous
//
#include <hip/hip_runtime.h>
#include <cstdint>
#include <cstddef>

typedef unsigned short u16;
typedef __bf16 bf16x8 __attribute__((ext_vector_type(8)));
typedef __bf16 bf16x2 __attribute__((ext_vector_type(2)));
typedef float f32x4 __attribute__((ext_vector_type(4)));
typedef float f32x16 __attribute__((ext_vector_type(16)));

#define B_   4
#define T_   2048
#define H_   1024
#define NH_  16
#define DH_  64
#define M_   (B_ * T_)      // 8192
#define KDIM 1024
// SCALE * log2(e): scores computed directly in log2 domain
#define QSCALE 0.18033688011112042f

#define BM 128
#define BN 128
#define BK 32

__device__ __forceinline__ u16 f2bf(float f) {
    unsigned u = __float_as_uint(f);
    unsigned r = (u + 0x7fffu + ((u >> 16) & 1u)) >> 16;  // RNE
    return (u16)r;
}

__device__ __forceinline__ unsigned packbf2(float a, float b) {
    bf16x2 v = { (__bf16)a, (__bf16)b };   // compiler emits v_cvt_pk_bf16_f32
    return __builtin_bit_cast(unsigned, v);
}

__device__ __forceinline__ float exp2_fast(float x) {
#if __has_builtin(__builtin_amdgcn_exp2f)
    return __builtin_amdgcn_exp2f(x);
#else
    return exp2f(x);
#endif
}

// in-place half-wave swap
__device__ __forceinline__ void plswap(unsigned &a, unsigned &b) {
#if __has_builtin(__builtin_amdgcn_permlane32_swap)
    auto r = __builtin_amdgcn_permlane32_swap(a, b, false, false);
    a = (unsigned)r[0]; b = (unsigned)r[1];
#else
    int hi = (threadIdx.x & 32);
    unsigned x = (unsigned)__shfl_xor((int)(hi ? b : a), 32);
    unsigned na = hi ? x : a;
    unsigned nb = hi ? b : x;
    a = na; b = nb;
#endif
}

__device__ __forceinline__ void gload16(const void* g, void* l) {
    __builtin_amdgcn_global_load_lds(
        (const __attribute__((address_space(1))) unsigned int*)g,
        (__attribute__((address_space(3))) unsigned int*)l,
        16, 0, 0);
}

__device__ __forceinline__ f32x16 mfma32(bf16x8 a, bf16x8 b, f32x16 c) {
    return __builtin_amdgcn_mfma_f32_32x32x16_bf16(a, b, c, 0, 0, 0);
}

// ---------------- fp32 -> bf16 converts (single launch, 6 jobs) ----------------
__global__ __launch_bounds__(256) void f2bf_hex(
    const float* s0, u16* d0, int n0, const float* s1, u16* d1, int n1,
    const float* s2, u16* d2, int n2, const float* s3, u16* d3, int n3,
    const float* s4, u16* d4, int n4j, const float* s5, u16* d5, int n5)
{
    const float* s; u16* d; int n;
    switch (blockIdx.y) {
        case 0: s = s0; d = d0; n = n0; break;
        case 1: s = s1; d = d1; n = n1; break;
        case 2: s = s2; d = d2; n = n2; break;
        case 3: s = s3; d = d3; n = n3; break;
        case 4: s = s4; d = d4; n = n4j; break;
        default: s = s5; d = d5; n = n5; break;
    }
    int i = blockIdx.x * blockDim.x + threadIdx.x;
    int stride = gridDim.x * blockDim.x;
    for (; i < n; i += stride) {
        float4 f = reinterpret_cast<const float4*>(s)[i];
        ushort4 o;
        o.x = f2bf(f.x); o.y = f2bf(f.y); o.z = f2bf(f.z); o.w = f2bf(f.w);
        reinterpret_cast<ushort4*>(d)[i] = o;
    }
}

// ---------------- 128x128 bf16 GEMM core  C = X * W^T ----------------
// T3/T4 (R10, validated): TRIPLE-buffered staging with counted vmcnt.
__device__ __forceinline__ void gemm_core(
    const u16* __restrict__ X, const u16* __restrict__ W,
    const float* __restrict__ bias,
    u16* __restrict__ dst_bf, float* __restrict__ dst_f,
    float scale, int mode, int r0, int c0)
{
    __shared__ u16 lds[24576];   // 49,152 B: 3 staging buffers x 16KB
    char* const base = (char*)lds;

    const int tid = threadIdx.x;
    const int wid = tid >> 6;
    const int l15 = tid & 15;
    const int l4  = (tid & 63) >> 4;
    const int wr = wid >> 1, wc = wid & 1;

    const u16* gA = X + (size_t)(r0 + (tid >> 2)) * KDIM + (tid & 3) * 8;
    const u16* gB = W + (size_t)(c0 + (tid >> 2)) * KDIM + (tid & 3) * 8;

    f32x4 acc[4][4];
#pragma unroll
    for (int m = 0; m < 4; ++m)
#pragma unroll
        for (int n = 0; n < 4; ++n) acc[m][n] = (f32x4){0.f, 0.f, 0.f, 0.f};

    const int arow = wr * 64 + l15;
    const int brow = wc * 64 + l15;

#define STAGEG(p, kt) do { \
    const u16* pa_ = gA + (kt) * BK; \
    const u16* pb_ = gB + (kt) * BK; \
    char* dA_ = base + (p) * 16384 + wid * 1024; \
    char* dB_ = dA_ + 8192; \
    gload16(pa_, dA_); gload16(pa_ + 64 * KDIM, dA_ + 4096); \
    gload16(pb_, dB_); gload16(pb_ + 64 * KDIM, dB_ + 4096); } while (0)

#define COMPUTE(p) do { \
    const char* bufp = base + (p) * 16384; \
    bf16x8 a[4], b[4]; \
    _Pragma("unroll") \
    for (int m = 0; m < 4; ++m) \
        a[m] = *(const bf16x8*)(bufp + (arow + m * 16) * 64 + l4 * 16); \
    _Pragma("unroll") \
    for (int n = 0; n < 4; ++n) \
        b[n] = *(const bf16x8*)(bufp + 8192 + (brow + n * 16) * 64 + l4 * 16); \
    _Pragma("unroll") \
    for (int m = 0; m < 4; ++m) \
        _Pragma("unroll") \
        for (int n = 0; n < 4; ++n) \
            acc[m][n] = __builtin_amdgcn_mfma_f32_16x16x32_bf16(a[m], b[n], acc[m][n], 0, 0, 0); \
    } while (0)

    STAGEG(0, 0);
    STAGEG(1, 1);

    int p = 0;
    for (int kt = 0; kt < KDIM / BK - 1; ++kt) {
        asm volatile("s_waitcnt vmcnt(4) lgkmcnt(0)\n\ts_barrier" ::: "memory");
        if (kt + 2 < KDIM / BK) {
            int fp = p + 2; if (fp >= 3) fp -= 3;
            STAGEG(fp, kt + 2);
        }
        COMPUTE(p);
        ++p; if (p == 3) p = 0;
    }
    asm volatile("s_waitcnt vmcnt(0) lgkmcnt(0)\n\ts_barrier" ::: "memory");
    COMPUTE(p);
#undef COMPUTE
#undef STAGEG

    if (mode == 2) {
#pragma unroll
        for (int m = 0; m < 4; ++m)
#pragma unroll
            for (int n = 0; n < 4; ++n) {
                int cg = c0 + wc * 64 + n * 16 + l15;
                float bv = bias[cg];
                int rg = r0 + wr * 64 + m * 16 + l4 * 4;
#pragma unroll
                for (int j = 0; j < 4; ++j)
                    dst_f[(size_t)(rg + j) * H_ + cg] = acc[m][n][j] + bv;
            }
    } else if (mode == 0) {
        // stage C row-major in LDS ([128][136] u16), 16B coalesced stores
        __syncthreads();
        u16 (*ldsR)[136] = (u16(*)[136])lds;
#pragma unroll
        for (int m = 0; m < 4; ++m)
#pragma unroll
            for (int n = 0; n < 4; ++n) {
                int cl = wc * 64 + n * 16 + l15;
                float bv = bias[c0 + cl];
                int rl = wr * 64 + m * 16 + l4 * 4;
#pragma unroll
                for (int j = 0; j < 4; ++j)
                    ldsR[rl + j][cl] = f2bf((acc[m][n][j] + bv) * scale);
            }
        __syncthreads();
        int b2 = r0 >> 11, tb = r0 & (T_ - 1);
#pragma unroll
        for (int it = 0; it < 8; ++it) {
            int id = tid + it * 256;
            int row = id >> 4;
            int ch = id & 15;
            int head = (c0 >> 6) + (ch >> 3);
            int d0 = (ch & 7) * 8;
            uint4 v = *(const uint4*)&ldsR[row][ch * 8];
            *(uint4*)&dst_bf[(((size_t)(b2 * NH_ + head) * T_ + tb + row) << 6) + d0] = v;
        }
    } else {
        __syncthreads();
        u16 (*ldsT)[136] = (u16(*)[136])lds;
#pragma unroll
        for (int m = 0; m < 4; ++m)
#pragma unroll
            for (int n = 0; n < 4; ++n) {
                int cl = wc * 64 + n * 16 + l15;
                float bv = bias[c0 + cl];
                int rl = wr * 64 + m * 16 + l4 * 4;
#pragma unroll
                for (int j = 0; j < 4; ++j)
                    ldsT[cl][rl + j] = f2bf(acc[m][n][j] + bv);
            }
        __syncthreads();
        int b = r0 >> 11, tb = r0 & (T_ - 1);
#pragma unroll
        for (int it = 0; it < 8; ++it) {
            int chunk = tid + it * 256;
            int cl = chunk >> 4;
            int r8 = (chunk & 15) << 3;
            int cg = c0 + cl;
            int head = cg >> 6, d = cg & 63;
            uint4 v = *(const uint4*)&ldsT[cl][r8];
            *(uint4*)&dst_bf[((size_t)((b * NH_ + head) * DH_ + d) * T_) + tb + r8] = v;
        }
    }
}

// Fused QKV projection: grid (24,64). bx 0-7: Q, 8-15: K, 16-23: V.
__global__ __launch_bounds__(256) void gemm_qkv(
    const u16* __restrict__ qbf, const u16* __restrict__ vbf,
    const u16* __restrict__ Wqb, const u16* __restrict__ Wkb, const u16* __restrict__ Wvb,
    const float* __restrict__ bq, const float* __restrict__ bk, const float* __restrict__ bv,
    u16* __restrict__ Qd, u16* __restrict__ Kd, u16* __restrict__ Vtd)
{
    const int orig = blockIdx.y * 24 + blockIdx.x;
    const int swz = (orig & 7) * 192 + (orig >> 3);
    const int bx = swz % 24;
    const int by = swz / 24;
    const int seg = bx >> 3;
    const int r0 = by * BM;
    const int c0 = (bx & 7) * BN;

    if (seg == 0)
        gemm_core(qbf, Wqb, bq, Qd, nullptr, QSCALE, 0, r0, c0);
    else if (seg == 1)
        gemm_core(vbf, Wkb, bk, Kd, nullptr, 1.0f, 0, r0, c0);
    else
        gemm_core(vbf, Wvb, bv, Vtd, nullptr, 1.0f, 1, r0, c0);
}

// Output projection: grid (8,64). XCD swizzle chunk=64.
__global__ __launch_bounds__(256) void gemm_out(
    const u16* __restrict__ AO, const u16* __restrict__ Wob,
    const float* __restrict__ bo, float* __restrict__ out)
{
    const int orig = blockIdx.y * 8 + blockIdx.x;
    const int swz = (orig & 7) * 64 + (orig >> 3);
    const int bx = swz & 7;
    const int by = swz >> 3;
    gemm_core(AO, Wob, bo, nullptr, out, 1.0f, 2, by * BM, bx * BN);
}

// ---------------- flash attention: swapped-operand 32x32, Q-width 64 ----
// R6/R10-proven 82.7us kernel (dual-buffer, 32KB LDS, VGPR 116). Structural
// floor: 116 arch + 64 acc = 180 unified regs -> 2 waves/SIMD bucket; 74%
// combined MFMA+VALU issue = this structure's ceiling (verified R4/R6/R9/R11).
#define KVB 64

__global__ __launch_bounds__(256, 2) void attn64(
    const u16* __restrict__ Q, const u16* __restrict__ K,
    const u16* __restrict__ Vt, u16* __restrict__ AO)
{
    __shared__ u16 lds[16384];
    char* const base = (char*)lds;

    const int tid = threadIdx.x;
    const int wid = tid >> 6;
    const int lane = tid & 63;
    const int l31 = lane & 31;
    const int hi = lane >> 5;

    const int orig = blockIdx.y * 8 + blockIdx.x;
    const int swz = (orig & 7) * 64 + (orig >> 3);
    const int bn = swz >> 3;
    const int q0w = (swz & 7) * 256 + wid * 64;
    const int b = bn >> 4, head = bn & 15;

    const u16* Qb = Q + ((size_t)bn * T_ + q0w + l31) * DH_;
    const u16* Kb = K + (size_t)bn * T_ * DH_;
    const u16* Vb = Vt + (size_t)bn * DH_ * T_;

    bf16x8 qfa[4], qfb[4];
#pragma unroll
    for (int c = 0; c < 4; ++c) {
        qfa[c] = *(const bf16x8*)(Qb + c * 16 + hi * 8);
        qfb[c] = *(const bf16x8*)(Qb + 32 * DH_ + c * 16 + hi * 8);
    }

    f32x16 accO00, accO01, accO10, accO11;
#pragma unroll
    for (int r = 0; r < 16; ++r) {
        accO00[r] = 0.f; accO01[r] = 0.f;
        accO10[r] = 0.f; accO11[r] = 0.f;
    }
    float la = 0.f, lb = 0.f;

    const int srow = tid >> 3;
    const int scsw = (tid & 7) ^ ((tid >> 3) & 7);
    const int rowsw = l31 & 7;

    const u16* kSrc = Kb + (size_t)srow * DH_ + scsw * 8;
    const u16* vSrc = Vb + (size_t)srow * T_ + scsw * 8;

#define STAGE(dK, dV) do { \
    gload16(kSrc,            (dK) + tid * 16); \
    gload16(kSrc + 32 * DH_, (dK) + 4096 + tid * 16); \
    gload16(vSrc,            (dV) + tid * 16); \
    gload16(vSrc + 32 * T_,  (dV) + 4096 + tid * 16); \
    kSrc += KVB * DH_; vSrc += KVB; } while (0)

    char* const kb0 = base;
    char* const vb0 = base + 8192;
    char* const kb1 = base + 16384;
    char* const vb1 = base + 24576;

    auto process = [&](const char* kc, const char* vc) {
        f32x16 sA0, sA1, sB0, sB1;
#pragma unroll
        for (int r = 0; r < 16; ++r) { sA0[r] = 0.f; sA1[r] = 0.f; sB0[r] = 0.f; sB1[r] = 0.f; }
        __builtin_amdgcn_s_setprio(1);
#pragma unroll
        for (int c = 0; c < 4; ++c) {
            const int c16 = ((2 * c + hi) ^ rowsw) * 16;
            bf16x8 k0 = *(const bf16x8*)(kc + l31 * 128 + c16);
            bf16x8 k1 = *(const bf16x8*)(kc + 4096 + l31 * 128 + c16);
            sA0 = mfma32(k0, qfa[c], sA0);
            sA1 = mfma32(k1, qfa[c], sA1);
            sB0 = mfma32(k0, qfb[c], sB0);
            sB1 = mfma32(k1, qfb[c], sB1);
        }
        __builtin_amdgcn_s_setprio(0);

#pragma unroll
        for (int r = 0; r < 16; ++r) {
            sA0[r] = exp2_fast(sA0[r]);
            sA1[r] = exp2_fast(sA1[r]);
            sB0[r] = exp2_fast(sB0[r]);
            sB1[r] = exp2_fast(sB1[r]);
        }
        float ta = 0.f, tb2 = 0.f;
#pragma unroll
        for (int r = 0; r < 16; ++r) {
            ta  += sA0[r] + sA1[r];
            tb2 += sB0[r] + sB1[r];
        }
        la += ta; lb += tb2;

        unsigned w0a[8], w1a[8], w0b[8], w1b[8];
#pragma unroll
        for (int k2 = 0; k2 < 8; ++k2) {
            w0a[k2] = packbf2(sA0[2 * k2], sA0[2 * k2 + 1]);
            w1a[k2] = packbf2(sA1[2 * k2], sA1[2 * k2 + 1]);
            w0b[k2] = packbf2(sB0[2 * k2], sB0[2 * k2 + 1]);
            w1b[k2] = packbf2(sB1[2 * k2], sB1[2 * k2 + 1]);
        }
        plswap(w0a[0], w0a[2]); plswap(w0a[1], w0a[3]);
        plswap(w0a[4], w0a[6]); plswap(w0a[5], w0a[7]);
        plswap(w1a[0], w1a[2]); plswap(w1a[1], w1a[3]);
        plswap(w1a[4], w1a[6]); plswap(w1a[5], w1a[7]);
        plswap(w0b[0], w0b[2]); plswap(w0b[1], w0b[3]);
        plswap(w0b[4], w0b[6]); plswap(w0b[5], w0b[7]);
        plswap(w1b[0], w1b[2]); plswap(w1b[1], w1b[3]);
        plswap(w1b[4], w1b[6]); plswap(w1b[5], w1b[7]);

        __builtin_amdgcn_s_setprio(1);
#pragma unroll
        for (int ks = 0; ks < 4; ++ks) {
            union { unsigned w[4]; bf16x8 v; } pa, pb;
            const unsigned* sa_ = (ks < 2) ? w0a : w1a;
            const unsigned* sb_ = (ks < 2) ? w0b : w1b;
            const int o = (ks & 1) * 4;
            pa.w[0] = sa_[o + 0]; pa.w[1] = sa_[o + 1];
            pa.w[2] = sa_[o + 2]; pa.w[3] = sa_[o + 3];
            pb.w[0] = sb_[o + 0]; pb.w[1] = sb_[o + 1];
            pb.w[2] = sb_[o + 2]; pb.w[3] = sb_[o + 3];
            const int c16 = ((2 * ks + hi) ^ rowsw) * 16;
            bf16x8 v0f = *(const bf16x8*)(vc + l31 * 128 + c16);
            bf16x8 v1f = *(const bf16x8*)(vc + 4096 + l31 * 128 + c16);
            accO00 = mfma32(v0f, pa.v, accO00);
            accO01 = mfma32(v1f, pa.v, accO01);
            accO10 = mfma32(v0f, pb.v, accO10);
            accO11 = mfma32(v1f, pb.v, accO11);
        }
        __builtin_amdgcn_s_setprio(0);
    };

    STAGE(kb0, vb0);
    __syncthreads();

    for (int it = 0; it < T_ / KVB; it += 2) {
        STAGE(kb1, vb1);
        process(kb0, vb0);
        __syncthreads();
        if (it + 2 < T_ / KVB) STAGE(kb0, vb0);
        process(kb1, vb1);
        __syncthreads();
    }

    la += __shfl_xor(la, 32);
    lb += __shfl_xor(lb, 32);

    char* myO = base + wid * 8192;
    float inva = 1.f / la;
    float invb = 1.f / lb;
#pragma unroll
    for (int n = 0; n < 2; ++n)
#pragma unroll
        for (int r = 0; r < 16; ++r) {
            int d = n * 32 + (r & 3) + 8 * (r >> 2) + 4 * hi;
            int c16 = (d >> 3) ^ rowsw;
            float va = (n == 0 ? accO00[r] : accO01[r]) * inva;
            float vb2 = (n == 0 ? accO10[r] : accO11[r]) * invb;
            *(u16*)(myO + l31 * 128 + c16 * 16 + (d & 7) * 2) = f2bf(va);
            *(u16*)(myO + (32 + l31) * 128 + c16 * 16 + (d & 7) * 2) = f2bf(vb2);
        }
    asm volatile("s_waitcnt lgkmcnt(0)" ::: "memory");
#pragma unroll
    for (int it = 0; it < 8; ++it) {
        int id = lane + it * 64;
        int row = id >> 3;
        int c = id & 7;
        int c16s = c ^ (row & 7);
        uint4 val = *(const uint4*)(myO + row * 128 + c16s * 16);
        *(uint4*)&AO[(size_t)(b * T_ + q0w + row) * (NH_ * DH_) + head * DH_ + c * 8] = val;
    }
#undef STAGE
}

// ---------------- host launch ----------------
extern "C" void kernel_launch(void* const* d_in, const int* in_sizes, int n_in,
                              void* d_out, int out_size, void* d_ws, size_t ws_size,
                              hipStream_t stream)
{
    const float* query = (const float*)d_in[0];
    const float* value = (const float*)d_in[1];
    const float* Wq = (const float*)d_in[2];
    const float* bq = (const float*)d_in[3];
    const float* Wk = (const float*)d_in[4];
    const float* bk = (const float*)d_in[5];
    const float* Wv = (const float*)d_in[6];
    const float* bv = (const float*)d_in[7];
    const float* Wo = (const float*)d_in[8];
    const float* bo = (const float*)d_in[9];
    float* out = (float*)d_out;

    u16* ws = (u16*)d_ws;
    const size_t E8M = (size_t)8 << 20;
    u16* qbf = ws;
    u16* vbf = ws + E8M;
    u16* Wqb = ws + 2 * E8M;
    u16* Wkb = Wqb + (1u << 20);
    u16* Wvb = Wkb + (1u << 20);
    u16* Wob = Wvb + (1u << 20);
    u16* Qd  = Wob + (1u << 20);
    u16* Kd  = Qd + E8M;
    u16* Vtd = Kd + E8M;
    u16* AO  = Vtd + E8M;

    const int nBig = (B_ * T_ * H_) / 4;
    const int nW   = (KDIM * KDIM) / 4;
    f2bf_hex<<<dim3(512, 6), 256, 0, stream>>>(
        query, qbf, nBig, value, vbf, nBig,
        Wq, Wqb, nW, Wk, Wkb, nW, Wv, Wvb, nW, Wo, Wob, nW);

    gemm_qkv<<<dim3(24, 64), 256, 0, stream>>>(qbf, vbf, Wqb, Wkb, Wvb,
                                               bq, bk, bv, Qd, Kd, Vtd);

    attn64<<<dim3(8, 64), 256, 0, stream>>>(Qd, Kd, Vtd, AO);

    gemm_out<<<dim3(8, 64), 256, 0, stream>>>(AO, Wob, bo, out);
}